// Round 1
// baseline (84.247 us; speedup 1.0000x reference)
//
#include <hip/hip_runtime.h>
#include <math.h>

#define PAD 4
#define CLIPV 0.03f

struct W9 { float g[9]; };

__device__ __forceinline__ int reflect_idx(int i, int n) {
    if (i < 0) i = -i;
    if (i >= n) i = 2 * n - 2 - i;
    return i;
}

// ---------------------------------------------------------------------------
// Kernel A: convolve along W then H for one z-plane, 32x32 output tile/block.
// LDS: 40x40 input tile (+reflect halo), 40x32 W-convolved intermediate.
// ---------------------------------------------------------------------------
__global__ __launch_bounds__(256) void conv_wh(const float* __restrict__ in,
                                               float* __restrict__ out, W9 wt) {
    __shared__ float sIn[40][40];   // rows: h (with halo), cols: w (with halo)
    __shared__ float sT[40][32];    // W-convolved, still h-halo

    const int wb = blockIdx.x * 32;
    const int hb = blockIdx.y * 32;
    const int z  = blockIdx.z;
    const float* plane = in + (size_t)z * 65536;
    const int tid = threadIdx.x;

    // stage 0: load 40x40 input tile with reflect mapping
    for (int idx = tid; idx < 1600; idx += 256) {
        int r = idx / 40, c = idx - r * 40;
        int gr = reflect_idx(hb - PAD + r, 256);
        int gc = reflect_idx(wb - PAD + c, 256);
        sIn[r][c] = plane[gr * 256 + gc];
    }
    __syncthreads();

    // stage 1: conv along W -> sT[40][32]
    for (int idx = tid; idx < 1280; idx += 256) {
        int r = idx >> 5, c = idx & 31;
        float acc = 0.f;
        #pragma unroll
        for (int j = 0; j < 9; ++j) acc = fmaf(wt.g[j], sIn[r][c + j], acc);
        sT[r][c] = acc;
    }
    __syncthreads();

    // stage 2: conv along H -> global tmp
    for (int idx = tid; idx < 1024; idx += 256) {
        int r = idx >> 5, c = idx & 31;
        float acc = 0.f;
        #pragma unroll
        for (int j = 0; j < 9; ++j) acc = fmaf(wt.g[j], sT[r + j][c], acc);
        out[(size_t)z * 65536 + (size_t)(hb + r) * 256 + (wb + c)] = acc;
    }
}

// ---------------------------------------------------------------------------
// Kernel B: convolve along D with a rolling 9-plane register window (float4
// per thread), fused with the clip against the original input.
// Each block: 1024 consecutive floats of a plane (256 thr x float4),
// a z-chunk of 32 planes. Boundary z handled by reflect-mapped re-loads
// (L2-hot, boundary chunks only).
// ---------------------------------------------------------------------------
__global__ __launch_bounds__(256) void conv_d_clip(const float* __restrict__ tmp,
                                                   const float* __restrict__ x,
                                                   float* __restrict__ out, W9 wt) {
    const int tid = threadIdx.x;
    const size_t c4 = (size_t)blockIdx.x * 256 + tid;   // float4 index in plane [0,16384)
    const int z0 = blockIdx.y * 32;

    const float4* t4  = (const float4*)tmp;
    const float4* x4p = (const float4*)x;
    float4*       o4  = (float4*)out;

    float4 w[9];
    #pragma unroll
    for (int j = 0; j < 8; ++j) {
        int zf = reflect_idx(z0 - PAD + j, 256);
        w[j] = t4[(size_t)zf * 16384 + c4];
    }

    for (int z = z0; z < z0 + 32; ++z) {
        int zf = reflect_idx(z + PAD, 256);
        w[8] = t4[(size_t)zf * 16384 + c4];

        float4 acc;
        acc.x = 0.f; acc.y = 0.f; acc.z = 0.f; acc.w = 0.f;
        #pragma unroll
        for (int j = 0; j < 9; ++j) {
            acc.x = fmaf(wt.g[j], w[j].x, acc.x);
            acc.y = fmaf(wt.g[j], w[j].y, acc.y);
            acc.z = fmaf(wt.g[j], w[j].z, acc.z);
            acc.w = fmaf(wt.g[j], w[j].w, acc.w);
        }

        float4 xv = x4p[(size_t)z * 16384 + c4];
        float4 r;
        r.x = fmaxf(fminf(xv.x, acc.x + CLIPV), acc.x - CLIPV);
        r.y = fmaxf(fminf(xv.y, acc.y + CLIPV), acc.y - CLIPV);
        r.z = fmaxf(fminf(xv.z, acc.z + CLIPV), acc.z - CLIPV);
        r.w = fmaxf(fminf(xv.w, acc.w + CLIPV), acc.w - CLIPV);
        o4[(size_t)z * 16384 + c4] = r;

        #pragma unroll
        for (int j = 0; j < 8; ++j) w[j] = w[j + 1];
    }
}

extern "C" void kernel_launch(void* const* d_in, const int* in_sizes, int n_in,
                              void* d_out, int out_size, void* d_ws, size_t ws_size,
                              hipStream_t stream) {
    const float* x = (const float*)d_in[0];
    float* out = (float*)d_out;
    float* tmp = (float*)d_ws;   // needs 256 MB

    // normalized 1-D Gaussian weights (separable form of the reference's 3-D kernel)
    W9 wt;
    {
        double g[9], s = 0.0;
        const double sigma = 9.0 / 4.0;
        for (int i = 0; i < 9; ++i) {
            double t = (i - 4.0) / sigma;
            g[i] = exp(-0.5 * t * t);
            s += g[i];
        }
        for (int i = 0; i < 9; ++i) wt.g[i] = (float)(g[i] / s);
    }

    dim3 gA(8, 8, 256);          // 32x32 tiles over 256x256 plane, 256 planes
    conv_wh<<<gA, dim3(256), 0, stream>>>(x, tmp, wt);

    dim3 gB(64, 8);              // 64 blocks/plane-chunk, 8 z-chunks of 32
    conv_d_clip<<<gB, dim3(256), 0, stream>>>(tmp, x, out, wt);
}

// Round 2
// 69.951 us; speedup vs baseline: 1.2044x; 1.2044x over previous
//
#include <hip/hip_runtime.h>
#include <math.h>

#define CLIPV 0.03f

struct W9 { float g[9]; };

__device__ __forceinline__ int reflect_idx(int i, int n) {
    if (i < 0) i = -i;
    if (i >= n) i = 2 * n - 2 - i;
    return i;
}

// ---------------------------------------------------------------------------
// Fully fused separable 3-D Gaussian + clip, single pass.
// Block: 32x32 (HxW) tile, marches a z-chunk of 16 output planes (+8 warmup).
// Per z-step: raw plane tile -> LDS (float4), W-conv (float4 sliding window)
// -> LDS, H-conv per-thread (each thread owns one (h, w4) float4 position),
// result pushed into a 9-deep float4 register ring for the D-conv. Raw center
// values kept in a 5-deep register ring for the clip. No intermediate global
// buffer, no x re-read.
// ---------------------------------------------------------------------------
__global__ __launch_bounds__(256) void smooth3d_fused(const float* __restrict__ x,
                                                      float* __restrict__ out, W9 wt) {
    __shared__ float sIn[40][40];   // raw tile: rows h-4..h+35, cols w-4..w+35
    __shared__ float sT[40][32];    // W-convolved, H halo kept

    const int wb = (blockIdx.x & 7) * 32;
    const int hb = (blockIdx.x >> 3) * 32;
    const int z0 = blockIdx.y * 16;

    const int t  = threadIdx.x;
    const int fc = (t & 7) * 4;     // this thread's float4 col within tile (floats)
    const int h  = t >> 3;          // this thread's row within tile (0..31)

    const bool wedge = (wb == 0) || (wb == 224);   // W-reflect needed (block-uniform)

    float4 rWH[9];    // rolling WH-convolved planes (z-window)
    float4 rX[5];     // rolling raw center values (for clip)

    for (int i = 0; i < 24; ++i) {
        const int zr = reflect_idx(z0 - 4 + i, 256);
        const float* plane = x + (size_t)zr * 65536;

        // ---- stage0: raw plane -> sIn (40 rows x 10 float4) ----
        if (!wedge) {
            for (int idx = t; idx < 400; idx += 256) {
                int r = idx / 10, c4 = (idx - r * 10) * 4;
                int gr = reflect_idx(hb - 4 + r, 256);
                *(float4*)&sIn[r][c4] =
                    *(const float4*)(plane + gr * 256 + (wb - 4) + c4);
            }
        } else {
            for (int idx = t; idx < 400; idx += 256) {
                int r = idx / 10, c4 = (idx - r * 10) * 4;
                int gr = reflect_idx(hb - 4 + r, 256);
                #pragma unroll
                for (int k = 0; k < 4; ++k) {
                    int gc = reflect_idx(wb - 4 + c4 + k, 256);
                    sIn[r][c4 + k] = plane[gr * 256 + gc];
                }
            }
        }
        __syncthreads();

        // ---- stage1: W-conv -> sT, and grab this thread's raw center ----
        for (int idx = t; idx < 320; idx += 256) {
            int r = idx >> 3, cb = (idx & 7) * 4;
            float4 A = *(const float4*)&sIn[r][cb];
            float4 B = *(const float4*)&sIn[r][cb + 4];
            float4 C = *(const float4*)&sIn[r][cb + 8];
            float sv[12] = {A.x, A.y, A.z, A.w, B.x, B.y, B.z, B.w,
                            C.x, C.y, C.z, C.w};
            float4 o;
            float ov[4];
            #pragma unroll
            for (int e = 0; e < 4; ++e) {
                float acc = 0.f;
                #pragma unroll
                for (int j = 0; j < 9; ++j) acc = fmaf(wt.g[j], sv[e + j], acc);
                ov[e] = acc;
            }
            o.x = ov[0]; o.y = ov[1]; o.z = ov[2]; o.w = ov[3];
            *(float4*)&sT[r][cb] = o;
        }
        float4 rv = *(const float4*)&sIn[h + 4][4 + fc];   // raw at (h, fc), this plane
        __syncthreads();

        // ---- stage2: H-conv at own position ----
        float4 wv;
        {
            float ax = 0.f, ay = 0.f, az = 0.f, aw = 0.f;
            #pragma unroll
            for (int j = 0; j < 9; ++j) {
                float4 v = *(const float4*)&sT[h + j][fc];
                ax = fmaf(wt.g[j], v.x, ax);
                ay = fmaf(wt.g[j], v.y, ay);
                az = fmaf(wt.g[j], v.z, az);
                aw = fmaf(wt.g[j], v.w, aw);
            }
            wv.x = ax; wv.y = ay; wv.z = az; wv.w = aw;
        }

        // ---- push rings ----
        #pragma unroll
        for (int k = 0; k < 8; ++k) rWH[k] = rWH[k + 1];
        rWH[8] = wv;
        #pragma unroll
        for (int k = 0; k < 4; ++k) rX[k] = rX[k + 1];
        rX[4] = rv;

        // ---- D-conv + clip + store (valid once ring is full) ----
        if (i >= 8) {
            const int z = z0 + i - 8;
            float ax = 0.f, ay = 0.f, az = 0.f, aw = 0.f;
            #pragma unroll
            for (int j = 0; j < 9; ++j) {
                ax = fmaf(wt.g[j], rWH[j].x, ax);
                ay = fmaf(wt.g[j], rWH[j].y, ay);
                az = fmaf(wt.g[j], rWH[j].z, az);
                aw = fmaf(wt.g[j], rWH[j].w, aw);
            }
            float4 xv = rX[0];
            float4 r;
            r.x = fmaxf(fminf(xv.x, ax + CLIPV), ax - CLIPV);
            r.y = fmaxf(fminf(xv.y, ay + CLIPV), ay - CLIPV);
            r.z = fmaxf(fminf(xv.z, az + CLIPV), az - CLIPV);
            r.w = fmaxf(fminf(xv.w, aw + CLIPV), aw - CLIPV);
            *(float4*)(out + (size_t)z * 65536 + (size_t)(hb + h) * 256 + wb + fc) = r;
        }
    }
}

extern "C" void kernel_launch(void* const* d_in, const int* in_sizes, int n_in,
                              void* d_out, int out_size, void* d_ws, size_t ws_size,
                              hipStream_t stream) {
    const float* x = (const float*)d_in[0];
    float* out = (float*)d_out;

    // normalized 1-D Gaussian weights (separable form of the reference kernel)
    W9 wt;
    {
        double g[9], s = 0.0;
        const double sigma = 9.0 / 4.0;
        for (int i = 0; i < 9; ++i) {
            double tt = (i - 4.0) / sigma;
            g[i] = exp(-0.5 * tt * tt);
            s += g[i];
        }
        for (int i = 0; i < 9; ++i) wt.g[i] = (float)(g[i] / s);
    }

    dim3 grid(64, 16);   // 8x8 tiles of 32x32, 16 z-chunks of 16 planes
    smooth3d_fused<<<grid, dim3(256), 0, stream>>>(x, out, wt);
}

// Round 3
// 67.531 us; speedup vs baseline: 1.2475x; 1.0358x over previous
//
#include <hip/hip_runtime.h>
#include <math.h>

#define CLIPV 0.03f

struct W9 { float g[9]; };

__device__ __forceinline__ int reflect_idx(int i, int n) {
    if (i < 0) i = -i;
    if (i >= n) i = 2 * n - 2 - i;
    return i;
}

// ---------------------------------------------------------------------------
// Fused separable 3-D Gaussian (K=9) + clip, single pass, software-pipelined.
// Block: 32x32 (HxW) tile, marches a z-chunk of 32 output planes (+8 warmup).
// Per z-step:
//   - issue global loads of NEXT raw plane tile -> registers (latency hidden)
//   - B1; W-conv from sIn[cur] -> sT (float4 sliding window); grab raw center
//   - B2; H-conv at own (h,w4); push 9-deep float4 z-ring; D-conv+clip+store
//   - ds_write staged regs -> sIn[cur^1]  (ping-pong, no extra barrier)
// XCD swizzle: chunk = bid&7 so each XCD owns one z-chunk; tile-halo re-reads
// are served by that XCD's L2.
// ---------------------------------------------------------------------------
__global__ __launch_bounds__(256) void smooth3d_fused(const float* __restrict__ x,
                                                      float* __restrict__ out, W9 wt) {
    __shared__ float sIn[2][40][40];   // ping-pong raw tile (h-4..h+35, w-4..w+35)
    __shared__ float sT[40][32];       // W-convolved, H halo kept

    const int bid   = blockIdx.x;
    const int chunk = bid & 7;         // z-chunk; == XCD id under %8 round-robin
    const int tile  = bid >> 3;        // 0..63
    const int wb = (tile & 7) * 32;
    const int hb = (tile >> 3) * 32;
    const int z0 = chunk * 32;

    const int t  = threadIdx.x;
    const int fc = (t & 7) * 4;        // this thread's float4 col (floats)
    const int h  = t >> 3;             // this thread's row (0..31)

    const bool wedge = (wb == 0) || (wb == 224);   // W-reflect needed (block-uniform)

    // staging-reg geometry (two slots: idx=t and idx=t+256, 400 total)
    const int r0 = t / 10, c0 = (t - r0 * 10) * 4;
    const int i1 = t + 256;
    const int r1 = i1 / 10, c1 = (i1 - r1 * 10) * 4;
    const int gr0 = reflect_idx(hb - 4 + r0, 256);
    const int gr1 = reflect_idx(hb - 4 + r1, 256);

    float4 stA, stB;                   // staged next-plane values

    // load one plane's tile into regs
    auto load_plane = [&](int zr, float4& a, float4& b) {
        const float* plane = x + (size_t)zr * 65536;
        if (!wedge) {
            a = *(const float4*)(plane + gr0 * 256 + (wb - 4) + c0);
            if (t < 144)
                b = *(const float4*)(plane + gr1 * 256 + (wb - 4) + c1);
        } else {
            float v[4];
            #pragma unroll
            for (int k = 0; k < 4; ++k)
                v[k] = plane[gr0 * 256 + reflect_idx(wb - 4 + c0 + k, 256)];
            a.x = v[0]; a.y = v[1]; a.z = v[2]; a.w = v[3];
            if (t < 144) {
                #pragma unroll
                for (int k = 0; k < 4; ++k)
                    v[k] = plane[gr1 * 256 + reflect_idx(wb - 4 + c1 + k, 256)];
                b.x = v[0]; b.y = v[1]; b.z = v[2]; b.w = v[3];
            }
        }
    };
    auto store_plane = [&](int buf, const float4& a, const float4& b) {
        *(float4*)&sIn[buf][r0][c0] = a;
        if (t < 144) *(float4*)&sIn[buf][r1][c1] = b;
    };

    float4 rWH[9];    // rolling WH-convolved planes (z-window)
    float4 rX[5];     // rolling raw center values (for clip)

    // prologue: plane for step 0 into sIn[0]
    load_plane(reflect_idx(z0 - 4, 256), stA, stB);
    store_plane(0, stA, stB);
    int cur = 0;

    for (int i = 0; i < 40; ++i) {
        // issue next plane's loads (latency overlapped with compute below)
        if (i < 39)
            load_plane(reflect_idx(z0 - 3 + i, 256), stA, stB);

        __syncthreads();   // sIn[cur] writes visible; prev-iter sT reads done

        // ---- stage1: W-conv from sIn[cur] -> sT; grab raw center ----
        {
            int idx = t;
            #pragma unroll
            for (int rep = 0; rep < 2; ++rep) {
                if (rep == 0 || t < 64) {
                    int r = idx >> 3, cb = (idx & 7) * 4;
                    float4 A = *(const float4*)&sIn[cur][r][cb];
                    float4 B = *(const float4*)&sIn[cur][r][cb + 4];
                    float4 C = *(const float4*)&sIn[cur][r][cb + 8];
                    float sv[12] = {A.x, A.y, A.z, A.w, B.x, B.y, B.z, B.w,
                                    C.x, C.y, C.z, C.w};
                    float ov[4];
                    #pragma unroll
                    for (int e = 0; e < 4; ++e) {
                        float acc = 0.f;
                        #pragma unroll
                        for (int j = 0; j < 9; ++j) acc = fmaf(wt.g[j], sv[e + j], acc);
                        ov[e] = acc;
                    }
                    float4 o; o.x = ov[0]; o.y = ov[1]; o.z = ov[2]; o.w = ov[3];
                    *(float4*)&sT[r][cb] = o;
                }
                idx += 256;
            }
        }
        float4 rv = *(const float4*)&sIn[cur][h + 4][4 + fc];
        __syncthreads();   // sT ready; all sIn[cur] reads done

        // ---- stage2: H-conv at own position ----
        float4 wv;
        {
            float ax = 0.f, ay = 0.f, az = 0.f, aw = 0.f;
            #pragma unroll
            for (int j = 0; j < 9; ++j) {
                float4 v = *(const float4*)&sT[h + j][fc];
                ax = fmaf(wt.g[j], v.x, ax);
                ay = fmaf(wt.g[j], v.y, ay);
                az = fmaf(wt.g[j], v.z, az);
                aw = fmaf(wt.g[j], v.w, aw);
            }
            wv.x = ax; wv.y = ay; wv.z = az; wv.w = aw;
        }

        // ---- push rings ----
        #pragma unroll
        for (int k = 0; k < 8; ++k) rWH[k] = rWH[k + 1];
        rWH[8] = wv;
        #pragma unroll
        for (int k = 0; k < 4; ++k) rX[k] = rX[k + 1];
        rX[4] = rv;

        // ---- D-conv + clip + store ----
        if (i >= 8) {
            const int z = z0 + i - 8;
            float ax = 0.f, ay = 0.f, az = 0.f, aw = 0.f;
            #pragma unroll
            for (int j = 0; j < 9; ++j) {
                ax = fmaf(wt.g[j], rWH[j].x, ax);
                ay = fmaf(wt.g[j], rWH[j].y, ay);
                az = fmaf(wt.g[j], rWH[j].z, az);
                aw = fmaf(wt.g[j], rWH[j].w, aw);
            }
            float4 xv = rX[0];
            float4 r;
            r.x = fmaxf(fminf(xv.x, ax + CLIPV), ax - CLIPV);
            r.y = fmaxf(fminf(xv.y, ay + CLIPV), ay - CLIPV);
            r.z = fmaxf(fminf(xv.z, az + CLIPV), az - CLIPV);
            r.w = fmaxf(fminf(xv.w, aw + CLIPV), aw - CLIPV);
            *(float4*)(out + (size_t)z * 65536 + (size_t)(hb + h) * 256 + wb + fc) = r;
        }

        // ---- commit staged next plane into the other buffer ----
        if (i < 39) store_plane(cur ^ 1, stA, stB);
        cur ^= 1;
    }
}

extern "C" void kernel_launch(void* const* d_in, const int* in_sizes, int n_in,
                              void* d_out, int out_size, void* d_ws, size_t ws_size,
                              hipStream_t stream) {
    const float* x = (const float*)d_in[0];
    float* out = (float*)d_out;

    // normalized 1-D Gaussian weights (separable form of the reference kernel)
    W9 wt;
    {
        double g[9], s = 0.0;
        const double sigma = 9.0 / 4.0;
        for (int i = 0; i < 9; ++i) {
            double tt = (i - 4.0) / sigma;
            g[i] = exp(-0.5 * tt * tt);
            s += g[i];
        }
        for (int i = 0; i < 9; ++i) wt.g[i] = (float)(g[i] / s);
    }

    // 512 blocks: 8 z-chunks (x32 planes) x 64 tiles (32x32)
    smooth3d_fused<<<dim3(512), dim3(256), 0, stream>>>(x, out, wt);
}